// Round 12
// baseline (465.493 us; speedup 1.0000x reference)
//
#include <hip/hip_runtime.h>
#include <hip/hip_bf16.h>
#include <type_traits>
#include <stdint.h>

typedef short bf16x8 __attribute__((ext_vector_type(8)));
typedef short short4v __attribute__((ext_vector_type(4)));
typedef float f32x4 __attribute__((ext_vector_type(4)));
typedef float f32x16 __attribute__((ext_vector_type(16)));

#define GLL16(gp, lp) __builtin_amdgcn_global_load_lds( \
    (const __attribute__((address_space(1))) void*)(gp), \
    (__attribute__((address_space(3))) void*)(lp), 16, 0, 0)

__device__ inline short f2bf(float f) {
    union { float f; uint32_t u; } v;
    v.f = f;
    uint32_t r = (v.u + 0x7FFFu + ((v.u >> 16) & 1u)) >> 16;
    return (short)(uint16_t)r;
}

__device__ inline bf16x8 cvt8(const float4& a, const float4& b) {
    bf16x8 o;
    o[0] = f2bf(a.x); o[1] = f2bf(a.y); o[2] = f2bf(a.z); o[3] = f2bf(a.w);
    o[4] = f2bf(b.x); o[5] = f2bf(b.y); o[6] = f2bf(b.z); o[7] = f2bf(b.w);
    return o;
}

__device__ inline uint32_t cvtpk(float lo, float hi) {
    uint32_t r;
    asm("v_cvt_pk_bf16_f32 %0, %1, %2" : "=v"(r) : "v"(lo), "v"(hi));
    return r;
}

__device__ inline bf16x8 mk8(uint32_t a, uint32_t b, uint32_t c, uint32_t d) {
    union { uint32_t u[4]; bf16x8 v; } t;
    t.u[0] = a; t.u[1] = b; t.u[2] = c; t.u[3] = d;
    return t.v;
}

// Verified shfl-based exchange (lane ^ 32).
__device__ inline void xchg_pf(const uint32_t c[8], bool hib, bf16x8& fA, bf16x8& fB) {
    uint32_t p0 = (uint32_t)__shfl_xor((int)c[0], 32);
    uint32_t p1 = (uint32_t)__shfl_xor((int)c[1], 32);
    uint32_t p2 = (uint32_t)__shfl_xor((int)c[2], 32);
    uint32_t p3 = (uint32_t)__shfl_xor((int)c[3], 32);
    fA = mk8(hib ? p2 : c[0], hib ? p3 : c[1], hib ? c[2] : p0, hib ? c[3] : p1);
    uint32_t p4 = (uint32_t)__shfl_xor((int)c[4], 32);
    uint32_t p5 = (uint32_t)__shfl_xor((int)c[5], 32);
    uint32_t p6 = (uint32_t)__shfl_xor((int)c[6], 32);
    uint32_t p7 = (uint32_t)__shfl_xor((int)c[7], 32);
    fB = mk8(hib ? p6 : c[4], hib ? p7 : c[5], hib ? c[6] : p4, hib ? c[7] : p5);
}

// Runtime-probe permlane32_swap semantics (round-11 verified working).
__device__ inline int probe_permlane_mode() {
#if defined(__has_builtin) && __has_builtin(__builtin_amdgcn_permlane32_swap)
    int lane = (int)(threadIdx.x & 63);
    int a = lane, b = lane + 1000;
    auto r = __builtin_amdgcn_permlane32_swap(a, b, false, false);
    int l0  = __builtin_amdgcn_readfirstlane(r[0]);
    int l32 = __builtin_amdgcn_readlane(r[0], 32);
    if (l0 == 0 && l32 == 1000) return 1;
    if (l0 == 1032 && l32 == 32) return 2;
    return 0;
#else
    return 0;
#endif
}

// ---------------- fused prep: 4x W-transpose + q/k/v f32->bf16 ----------------
__global__ __launch_bounds__(256) void prep(
    const float* __restrict__ Wq, const float* __restrict__ Wk,
    const float* __restrict__ Wv, const float* __restrict__ Wo,
    short* __restrict__ WqT, short* __restrict__ WkT,
    short* __restrict__ WvT, short* __restrict__ WoT,
    const float* __restrict__ q, const float* __restrict__ k, const float* __restrict__ v,
    short* __restrict__ Xq, short* __restrict__ Xk, short* __restrict__ Xv)
{
    __shared__ short Tt[64][65];
    const int K = 2048;
    int bid = blockIdx.x;
    int t = threadIdx.x;
    if (bid < 2560) {
        const float* W; short* T; int N; int l;
        if (bid < 1024)      { W = Wq; T = WqT; N = 2048; l = bid; }
        else if (bid < 1280) { W = Wk; T = WkT; N = 512;  l = bid - 1024; }
        else if (bid < 1536) { W = Wv; T = WvT; N = 512;  l = bid - 1280; }
        else                 { W = Wo; T = WoT; N = 2048; l = bid - 1536; }
        int nt = N >> 6;
        int n0 = (l % nt) * 64, k0 = (l / nt) * 64;
        int kl = t >> 2, nb = (t & 3) * 16;
        const float* wp = W + (size_t)(k0 + kl) * N + n0 + nb;
        #pragma unroll
        for (int j = 0; j < 16; ++j) Tt[nb + j][kl] = f2bf(wp[j]);
        __syncthreads();
        int nl = t >> 2, kb = (t & 3) * 16;
        short* op = T + (size_t)(n0 + nl) * K + k0 + kb;
        #pragma unroll
        for (int j = 0; j < 16; ++j) op[j] = Tt[nl][kb + j];
    } else {
        size_t tid = (size_t)(bid - 2560) * 256 + t;
        #pragma unroll
        for (int it = 0; it < 2; ++it) {
            size_t i = tid + (size_t)it * 524288;
            const float4* p;
            p = (const float4*)(q + i * 8);
            *(bf16x8*)(Xq + i * 8) = cvt8(p[0], p[1]);
            p = (const float4*)(k + i * 8);
            *(bf16x8*)(Xk + i * 8) = cvt8(p[0], p[1]);
            p = (const float4*)(v + i * 8);
            *(bf16x8*)(Xv + i * 8) = cvt8(p[0], p[1]);
        }
    }
}

// ---------------- fallback helpers ----------------
__global__ __launch_bounds__(256) void prepW(
    const float* __restrict__ Wq, const float* __restrict__ Wk,
    const float* __restrict__ Wv, const float* __restrict__ Wo,
    short* __restrict__ WqT, short* __restrict__ WkT,
    short* __restrict__ WvT, short* __restrict__ WoT)
{
    __shared__ short Tt[64][65];
    const int K = 2048;
    int bid = blockIdx.x;
    int t = threadIdx.x;
    const float* W; short* T; int N; int l;
    if (bid < 1024)      { W = Wq; T = WqT; N = 2048; l = bid; }
    else if (bid < 1280) { W = Wk; T = WkT; N = 512;  l = bid - 1024; }
    else if (bid < 1536) { W = Wv; T = WvT; N = 512;  l = bid - 1280; }
    else                 { W = Wo; T = WoT; N = 2048; l = bid - 1536; }
    int nt = N >> 6;
    int n0 = (l % nt) * 64, k0 = (l / nt) * 64;
    int kl = t >> 2, nb = (t & 3) * 16;
    const float* wp = W + (size_t)(k0 + kl) * N + n0 + nb;
    #pragma unroll
    for (int j = 0; j < 16; ++j) Tt[nb + j][kl] = f2bf(wp[j]);
    __syncthreads();
    int nl = t >> 2, kb = (t & 3) * 16;
    short* op = T + (size_t)(n0 + nl) * K + k0 + kb;
    #pragma unroll
    for (int j = 0; j < 16; ++j) op[j] = Tt[nl][kb + j];
}

__global__ __launch_bounds__(256) void cvtk(const float* __restrict__ in,
                                            short* __restrict__ out, int n8)
{
    int i = blockIdx.x * blockDim.x + threadIdx.x;
    int stride = gridDim.x * blockDim.x;
    for (; i < n8; i += stride) {
        const float4* p = (const float4*)(in + (size_t)i * 8);
        *(bf16x8*)(out + (size_t)i * 8) = cvt8(p[0], p[1]);
    }
}

__global__ __launch_bounds__(256) void transV(const short* __restrict__ Vb,
                                              short* __restrict__ Vt)
{
    __shared__ short T[64][65];
    int s0 = blockIdx.x * 64, d0 = blockIdx.y * 64, bg = blockIdx.z;
    int b = bg >> 2, g = bg & 3;
    int t = threadIdx.x;
    int sl = t >> 2, db = (t & 3) * 16;
    const short* vp = Vb + (size_t)(b * 2048 + s0 + sl) * 512 + g * 128 + d0 + db;
    #pragma unroll
    for (int j = 0; j < 16; ++j) T[db + j][sl] = vp[j];
    __syncthreads();
    int dl = t >> 2, sb = (t & 3) * 16;
    short* op = Vt + (size_t)(bg * 128 + d0 + dl) * 2048 + s0 + sb;
    #pragma unroll
    for (int j = 0; j < 16; ++j) op[j] = T[dl][sb + j];
}

// ---------------- bf16 GEMM core ----------------
template <typename TC>
__device__ __forceinline__ void gemm_core(
    const short* __restrict__ A, const short* __restrict__ BT,
    const float* __restrict__ bias, TC* __restrict__ C,
    int N, int K, int m0, int n0, short* As, short* Bs, int epi)
{
    const int t = threadIdx.x, w = t >> 6, lane = t & 63;
    const int lr = lane & 15, lg = lane >> 4;
    const int wm = (w >> 1) * 64, wn = (w & 1) * 64;
    f32x4 acc[4][4] = {};

    const int lrow = lane >> 3;
    const int lcg = (lane & 7) ^ (lrow & 7);
    const int sw = lr & 7;

    const short* abase[2]; const short* bbase[2];
    #pragma unroll
    for (int kc = 0; kc < 2; ++kc) {
        abase[kc] = &As[(wm + lr) * 64 + (((kc * 4 + lg) ^ sw) * 8)];
        bbase[kc] = &Bs[(wn + lr) * 64 + (((kc * 4 + lg) ^ sw) * 8)];
    }
    const short* asrc = A  + (size_t)(m0 + w * 32 + lrow) * K + lcg * 8;
    const short* bsrc = BT + (size_t)(n0 + w * 32 + lrow) * K + lcg * 8;
    short* adst = &As[(w * 32) * 64];
    short* bdst = &Bs[(w * 32) * 64];

    for (int kk = 0; kk < K; kk += 64) {
        __syncthreads();
        #pragma unroll
        for (int i = 0; i < 4; ++i) {
            GLL16(asrc + (size_t)i * 8 * K, adst + i * 512);
            GLL16(bsrc + (size_t)i * 8 * K, bdst + i * 512);
        }
        asrc += 64; bsrc += 64;
        __syncthreads();
        #pragma unroll
        for (int kc = 0; kc < 2; ++kc) {
            bf16x8 af[4], bfr[4];
            #pragma unroll
            for (int i = 0; i < 4; ++i) af[i] = *(const bf16x8*)(abase[kc] + i * 1024);
            #pragma unroll
            for (int j = 0; j < 4; ++j) bfr[j] = *(const bf16x8*)(bbase[kc] + j * 1024);
            #pragma unroll
            for (int i = 0; i < 4; ++i)
                #pragma unroll
                for (int j = 0; j < 4; ++j)
                    acc[i][j] = __builtin_amdgcn_mfma_f32_16x16x32_bf16(af[i], bfr[j], acc[i][j], 0, 0, 0);
        }
    }

    if constexpr (std::is_same<TC, short>::value) {
        if (epi == 1) {
            #pragma unroll
            for (int i = 0; i < 4; ++i) {
                #pragma unroll
                for (int j = 0; j < 4; ++j) {
                    int row = m0 + wm + i * 16 + lg * 4;
                    int col = n0 + wn + j * 16 + lr;
                    short4v s4;
                    #pragma unroll
                    for (int r = 0; r < 4; ++r) s4[r] = f2bf(acc[i][j][r] + bias[col]);
                    int bb = row >> 11, ss = row & 2047;
                    *(short4v*)((short*)C + ((size_t)(bb * 4 + (col >> 7)) * 128 + (col & 127)) * 2048 + ss) = s4;
                }
            }
            return;
        }
    }
    #pragma unroll
    for (int i = 0; i < 4; ++i) {
        #pragma unroll
        for (int j = 0; j < 4; ++j) {
            #pragma unroll
            for (int r = 0; r < 4; ++r) {
                int row = m0 + wm + i * 16 + lg * 4 + r;
                int col = n0 + wn + j * 16 + lr;
                float v = acc[i][j][r] + bias[col];
                if constexpr (std::is_same<TC, short>::value)
                    C[(size_t)row * N + col] = f2bf(v);
                else
                    C[(size_t)row * N + col] = v;
            }
        }
    }
}

template <typename TC>
__global__ __launch_bounds__(256) void gemm_std(
    const short* __restrict__ A, const short* __restrict__ BT,
    const float* __restrict__ bias, TC* __restrict__ C, int N, int K)
{
    __shared__ short As[128 * 64];
    __shared__ short Bs[128 * 64];
    int bid = blockIdx.x;
    int chunk = gridDim.x >> 3;
    int wg = (bid & 7) * chunk + (bid >> 3);
    int m0 = (wg & 31) * 128, n0 = (wg >> 5) * 128;
    gemm_core<TC>(A, BT, bias, C, N, K, m0, n0, As, Bs, 0);
}

__global__ __launch_bounds__(256) void gemm_qkv(
    const short* __restrict__ Xq, const short* __restrict__ Xk, const short* __restrict__ Xv,
    const short* __restrict__ WqT, const short* __restrict__ WkT, const short* __restrict__ WvT,
    const float* __restrict__ bq, const float* __restrict__ bk, const float* __restrict__ bv,
    short* __restrict__ Qb, short* __restrict__ Kb, short* __restrict__ Vt)
{
    __shared__ short As[128 * 64];
    __shared__ short Bs[128 * 64];
    int bid = blockIdx.x;
    int wg = (bid & 7) * 96 + (bid >> 3);
    const short* A; const short* BT; const float* bi; short* C; int N; int l; int epi;
    if (wg < 512)      { l = wg;       A = Xq; BT = WqT; bi = bq; C = Qb; N = 2048; epi = 0; }
    else if (wg < 640) { l = wg - 512; A = Xk; BT = WkT; bi = bk; C = Kb; N = 512;  epi = 0; }
    else               { l = wg - 640; A = Xv; BT = WvT; bi = bv; C = Vt; N = 512;  epi = 1; }
    int m0 = (l & 31) * 128, n0 = (l >> 5) * 128;
    gemm_core<short>(A, BT, bi, C, N, 2048, m0, n0, As, Bs, epi);
}

// ---------------- flash attention v12: in-block kv-split (8 waves, 4 waves/SIMD) ----------
// Waves 0-3: kv [0,1024); waves 4-7: kv [1024,2048) for the SAME 128 q rows.
// Per-half 32KB K/V LDS; LDS merge epilogue (round-7-validated split math).
__global__ __launch_bounds__(512, 4) void attn_kernel(
    const short* __restrict__ Qb, const short* __restrict__ Kb,
    const short* __restrict__ Vt, short* __restrict__ Ob)
{
    const int S = 2048;
    __shared__ short Ks[2 * 64 * 128];   // 32 KB: [half][kv 64][d 128], slot = c ^ (kv&15)
    __shared__ short Vs[2 * 128 * 64];   // 32 KB: [half][d 128][kv 64], slot = c ^ (d&7)
    __shared__ float Ml[4][64][2];       // 2 KB: upper-half (m,l) handoff

    int bid = blockIdx.x;
    int wg = (bid & 7) * 64 + (bid >> 3);
    const int qt = wg & 15, bh = wg >> 4;
    const int b = bh >> 4, h = bh & 15, g = h >> 2, bg = b * 4 + g;

    const int t = threadIdx.x, w = t >> 6, lane = t & 63;
    const int wq = w & 3, half = w >> 2;
    const int l5 = lane & 31, hi = lane >> 5;
    const bool hib = hi != 0;
    const int qg = b * S + qt * 128 + wq * 32 + l5;
    const float C = 1.44269504089f;

    const int mode = probe_permlane_mode();

    const short* qrow = Qb + (size_t)qg * 2048 + h * 128 + hi * 8;
    bf16x8 qf[8];
    #pragma unroll
    for (int dm = 0; dm < 8; ++dm)
        qf[dm] = *(const bf16x8*)(qrow + dm * 16);

    f32x16 o[4] = {};
    float m = -1e30f, l = 0.0f;

    // staging sources (v11 maps + half offset)
    const int sr4 = lane >> 4, sc4 = lane & 15;
    const int sr8 = lane >> 3, sc8 = lane & 7;
    const short* ksrc[4]; const short* vsrc[4];
    #pragma unroll
    for (int i = 0; i < 4; ++i) {
        int kr = wq * 16 + i * 4 + sr4;
        ksrc[i] = Kb + (size_t)(b * S + half * 1024 + kr) * 512 + g * 128 + ((sc4 ^ (kr & 15)) * 8);
        int d = wq * 32 + i * 8 + sr8;
        vsrc[i] = Vt + (size_t)(bg * 128 + d) * 2048 + half * 1024 + ((sc8 ^ (d & 7)) * 8);
    }

    int kx[8];
    #pragma unroll
    for (int dm = 0; dm < 8; ++dm)
        kx[dm] = (((dm * 2 + hi) ^ (l5 & 15)) * 8);
    int va[4];
    #pragma unroll
    for (int j = 0; j < 4; ++j)
        va[j] = (((2 * j + hi) ^ (l5 & 7)) * 8);

    short* kd = Ks + half * 8192 + (wq * 16) * 128 + lane * 8;
    short* vd = Vs + half * 8192 + (wq * 32) * 64 + lane * 8;

    bf16x8 kreg[4], vreg[4];
    #pragma unroll
    for (int i = 0; i < 4; ++i) {
        kreg[i] = *(const bf16x8*)(ksrc[i]);
        vreg[i] = *(const bf16x8*)(vsrc[i]);
    }

    const int NT = 1024 / 64;   // 16 tiles per half
    for (int ti = 0; ti < NT; ++ti) {
        __syncthreads();
        #pragma unroll
        for (int i = 0; i < 4; ++i) {
            *(bf16x8*)(kd + i * 512) = kreg[i];
            *(bf16x8*)(vd + i * 512) = vreg[i];
        }
        __syncthreads();
        if (ti + 1 < NT) {
            size_t ko = (size_t)(ti + 1) * 64 * 512;
            int vo = (ti + 1) * 64;
            #pragma unroll
            for (int i = 0; i < 4; ++i) {
                kreg[i] = *(const bf16x8*)(ksrc[i] + ko);
                vreg[i] = *(const bf16x8*)(vsrc[i] + vo);
            }
        }

        // ---- QK^T (swapped) ----
        const short* KB = Ks + half * 8192 + l5 * 128;
        f32x16 p0 = {}, p1 = {};
        __builtin_amdgcn_s_setprio(1);
        #pragma unroll
        for (int dm = 0; dm < 8; ++dm) {
            bf16x8 k0 = *(const bf16x8*)(KB + kx[dm]);
            bf16x8 k1 = *(const bf16x8*)(KB + 4096 + kx[dm]);
            p0 = __builtin_amdgcn_mfma_f32_32x32x16_bf16(k0, qf[dm], p0, 0, 0, 0);
            p1 = __builtin_amdgcn_mfma_f32_32x32x16_bf16(k1, qf[dm], p1, 0, 0, 0);
        }
        __builtin_amdgcn_s_setprio(0);

        // ---- online softmax ----
        float mx = -1e30f;
        #pragma unroll
        for (int e = 0; e < 16; ++e) mx = fmaxf(mx, fmaxf(p0[e], p1[e]));
        mx = fmaxf(mx, __shfl_xor(mx, 32));
        if (__any(mx > m)) {
            float mn = fmaxf(m, mx);
            float sf = exp2f((m - mn) * C);
            m = mn; l *= sf;
            #pragma unroll
            for (int dblk = 0; dblk < 4; ++dblk)
                #pragma unroll
                for (int e = 0; e < 16; ++e) o[dblk][e] *= sf;
        }
        float nmc = -m * C;
        #pragma unroll
        for (int e = 0; e < 16; ++e) {
            p0[e] = exp2f(fmaf(p0[e], C, nmc));
            p1[e] = exp2f(fmaf(p1[e], C, nmc));
        }
        float rs = 0.0f;
        #pragma unroll
        for (int e = 0; e < 16; ++e) rs += p0[e] + p1[e];
        rs += __shfl_xor(rs, 32);
        l += rs;

        // ---- P -> bf16 B-fragments ----
        uint32_t c0[8], c1[8];
        #pragma unroll
        for (int i = 0; i < 8; ++i) {
            c0[i] = cvtpk(p0[2 * i], p0[2 * i + 1]);
            c1[i] = cvtpk(p1[2 * i], p1[2 * i + 1]);
        }
        bf16x8 pf[4];
#if defined(__has_builtin) && __has_builtin(__builtin_amdgcn_permlane32_swap)
        if (mode == 1) {
            auto a0 = __builtin_amdgcn_permlane32_swap((int)c0[0], (int)c0[2], false, false);
            auto a1 = __builtin_amdgcn_permlane32_swap((int)c0[1], (int)c0[3], false, false);
            auto a2 = __builtin_amdgcn_permlane32_swap((int)c0[4], (int)c0[6], false, false);
            auto a3 = __builtin_amdgcn_permlane32_swap((int)c0[5], (int)c0[7], false, false);
            pf[0] = mk8((uint32_t)a0[0], (uint32_t)a1[0], (uint32_t)a0[1], (uint32_t)a1[1]);
            pf[1] = mk8((uint32_t)a2[0], (uint32_t)a3[0], (uint32_t)a2[1], (uint32_t)a3[1]);
            auto b0 = __builtin_amdgcn_permlane32_swap((int)c1[0], (int)c1[2], false, false);
            auto b1 = __builtin_amdgcn_permlane32_swap((int)c1[1], (int)c1[3], false, false);
            auto b2 = __builtin_amdgcn_permlane32_swap((int)c1[4], (int)c1[6], false, false);
            auto b3 = __builtin_amdgcn_permlane32_swap((int)c1[5], (int)c1[7], false, false);
            pf[2] = mk8((uint32_t)b0[0], (uint32_t)b1[0], (uint32_t)b0[1], (uint32_t)b1[1]);
            pf[3] = mk8((uint32_t)b2[0], (uint32_t)b3[0], (uint32_t)b2[1], (uint32_t)b3[1]);
        } else if (mode == 2) {
            auto a0 = __builtin_amdgcn_permlane32_swap((int)c0[2], (int)c0[0], false, false);
            auto a1 = __builtin_amdgcn_permlane32_swap((int)c0[3], (int)c0[1], false, false);
            auto a2 = __builtin_amdgcn_permlane32_swap((int)c0[6], (int)c0[4], false, false);
            auto a3 = __builtin_amdgcn_permlane32_swap((int)c0[7], (int)c0[5], false, false);
            pf[0] = mk8((uint32_t)a0[1], (uint32_t)a1[1], (uint32_t)a0[0], (uint32_t)a1[0]);
            pf[1] = mk8((uint32_t)a2[1], (uint32_t)a3[1], (uint32_t)a2[0], (uint32_t)a3[0]);
            auto b0 = __builtin_amdgcn_permlane32_swap((int)c1[2], (int)c1[0], false, false);
            auto b1 = __builtin_amdgcn_permlane32_swap((int)c1[3], (int)c1[1], false, false);
            auto b2 = __builtin_amdgcn_permlane32_swap((int)c1[6], (int)c1[4], false, false);
            auto b3 = __builtin_amdgcn_permlane32_swap((int)c1[7], (int)c1[5], false, false);
            pf[2] = mk8((uint32_t)b0[1], (uint32_t)b1[1], (uint32_t)b0[0], (uint32_t)b1[0]);
            pf[3] = mk8((uint32_t)b2[1], (uint32_t)b3[1], (uint32_t)b2[0], (uint32_t)b3[0]);
        } else
#endif
        {
            xchg_pf(c0, hib, pf[0], pf[1]);
            xchg_pf(c1, hib, pf[2], pf[3]);
        }

        // ---- PV ----
        const short* VB = Vs + half * 8192 + l5 * 64;
        __builtin_amdgcn_s_setprio(1);
        #pragma unroll
        for (int dblk = 0; dblk < 4; ++dblk) {
            const short* vb = VB + dblk * 2048;
            #pragma unroll
            for (int j = 0; j < 4; ++j) {
                bf16x8 vf = *(const bf16x8*)(vb + va[j]);
                o[dblk] = __builtin_amdgcn_mfma_f32_32x32x16_bf16(vf, pf[j], o[dblk], 0, 0, 0);
            }
        }
        __builtin_amdgcn_s_setprio(0);
    }

    // ---- merge epilogue: combine half 0/1 via LDS (two 32KB passes) ----
    __syncthreads();
    float* F = (float*)Ks;   // reuse K LDS (32KB) as transfer buffer
    if (half == 1) {
        Ml[wq][lane][0] = m;
        Ml[wq][lane][1] = l;
        float* dst = F + wq * 2048 + lane * 32;
        #pragma unroll
        for (int e = 0; e < 16; ++e) { dst[e] = o[0][e]; dst[16 + e] = o[1][e]; }
    }
    __syncthreads();
    float e1 = 1.0f, e2 = 0.0f, inv = 0.0f;
    if (half == 0) {
        float m2 = Ml[wq][lane][0], l2 = Ml[wq][lane][1];
        float mm = fmaxf(m, m2);
        e1 = exp2f((m - mm) * C);
        e2 = exp2f((m2 - mm) * C);
        inv = 1.0f / (l * e1 + l2 * e2);
        const float* src = F + wq * 2048 + lane * 32;
        #pragma unroll
        for (int e = 0; e < 16; ++e) {
            o[0][e] = o[0][e] * e1 + src[e] * e2;
            o[1][e] = o[1][e] * e1 + src[16 + e] * e2;
        }
    }
    __syncthreads();
    if (half == 1) {
        float* dst = F + wq * 2048 + lane * 32;
        #pragma unroll
        for (int e = 0; e < 16; ++e) { dst[e] = o[2][e]; dst[16 + e] = o[3][e]; }
    }
    __syncthreads();
    if (half == 0) {
        const float* src = F + wq * 2048 + lane * 32;
        #pragma unroll
        for (int e = 0; e < 16; ++e) {
            o[2][e] = o[2][e] * e1 + src[e] * e2;
            o[3][e] = o[3][e] * e1 + src[16 + e] * e2;
        }
        short* op = Ob + (size_t)qg * 2048 + h * 128 + hi * 4;
        #pragma unroll
        for (int dblk = 0; dblk < 4; ++dblk) {
            #pragma unroll
            for (int mm2 = 0; mm2 < 4; ++mm2) {
                short4v s4;
                #pragma unroll
                for (int e = 0; e < 4; ++e) s4[e] = f2bf(o[dblk][mm2 * 4 + e] * inv);
                *(short4v*)(op + dblk * 32 + mm2 * 8) = s4;
            }
        }
    }
}

extern "C" void kernel_launch(void* const* d_in, const int* in_sizes, int n_in,
                              void* d_out, int out_size, void* d_ws, size_t ws_size,
                              hipStream_t stream)
{
    const float* query = (const float*)d_in[0];
    const float* key   = (const float*)d_in[1];
    const float* value = (const float*)d_in[2];
    const float* Wq    = (const float*)d_in[3];
    const float* bq    = (const float*)d_in[4];
    const float* Wk    = (const float*)d_in[5];
    const float* bk    = (const float*)d_in[6];
    const float* Wv    = (const float*)d_in[7];
    const float* bv    = (const float*)d_in[8];
    const float* Wo    = (const float*)d_in[9];
    const float* bo    = (const float*)d_in[10];
    float* out = (float*)d_out;

    const int BS = 4096;
    char* ws = (char*)d_ws;
    dim3 blk(256);
    const size_t MB = 1048576;

    if (ws_size >= 96 * MB) {
        short* Xq  = (short*)(ws + 0);
        short* Xk  = (short*)(ws + 16 * MB);
        short* Xv  = (short*)(ws + 32 * MB);
        short* Qb  = (short*)(ws + 48 * MB);
        short* Kb  = (short*)(ws + 64 * MB);
        short* Vtg = (short*)(ws + 72 * MB);
        short* WqT = (short*)(ws + 76 * MB);
        short* WkT = (short*)(ws + 84 * MB);
        short* WvT = (short*)(ws + 86 * MB);
        short* WoT = (short*)(ws + 88 * MB);
        short* Ob  = Xq;  // Xq dead after gemm_qkv

        prep<<<4608, blk, 0, stream>>>(Wq, Wk, Wv, Wo, WqT, WkT, WvT, WoT,
                                       query, key, value, Xq, Xk, Xv);
        gemm_qkv<<<768, blk, 0, stream>>>(Xq, Xk, Xv, WqT, WkT, WvT, bq, bk, bv, Qb, Kb, Vtg);
        attn_kernel<<<512, dim3(512), 0, stream>>>(Qb, Kb, Vtg, Ob);
        gemm_std<float><<<512, blk, 0, stream>>>(Ob, WoT, bo, out, 2048, 2048);
    } else {
        short* Qb  = (short*)(ws + 0);
        short* Kb  = (short*)(ws + 16777216);
        short* Vb  = (short*)(ws + 20971520);
        short* Vtg = (short*)(ws + 25165824);
        short* WqT = (short*)(ws + 29360128);
        short* WkT = (short*)(ws + 37748736);
        short* WvT = (short*)(ws + 39845888);
        short* WoT = (short*)(ws + 41943040);
        short* Xbf = (short*)(ws + 50331648);

        prepW<<<2560, blk, 0, stream>>>(Wq, Wk, Wv, Wo, WqT, WkT, WvT, WoT);
        cvtk<<<2048, blk, 0, stream>>>(query, Xbf, BS * 2048 / 8);
        gemm_std<short><<<512, blk, 0, stream>>>(Xbf, WqT, bq, Qb, 2048, 2048);
        cvtk<<<2048, blk, 0, stream>>>(key, Xbf, BS * 2048 / 8);
        gemm_std<short><<<128, blk, 0, stream>>>(Xbf, WkT, bk, Kb, 512, 2048);
        cvtk<<<2048, blk, 0, stream>>>(value, Xbf, BS * 2048 / 8);
        gemm_std<short><<<128, blk, 0, stream>>>(Xbf, WvT, bv, Vb, 512, 2048);
        transV<<<dim3(32, 2, 8), blk, 0, stream>>>(Vb, Vtg);
        attn_kernel<<<512, dim3(512), 0, stream>>>(Qb, Kb, Vtg, Xbf);
        gemm_std<float><<<512, blk, 0, stream>>>(Xbf, WoT, bo, out, 2048, 2048);
    }
}

// Round 14
// 255.614 us; speedup vs baseline: 1.8211x; 1.8211x over previous
//
#include <hip/hip_runtime.h>
#include <hip/hip_bf16.h>
#include <type_traits>
#include <stdint.h>

typedef short bf16x8 __attribute__((ext_vector_type(8)));
typedef short short4v __attribute__((ext_vector_type(4)));
typedef float f32x4 __attribute__((ext_vector_type(4)));
typedef float f32x16 __attribute__((ext_vector_type(16)));

#define GLL16(gp, lp) __builtin_amdgcn_global_load_lds( \
    (const __attribute__((address_space(1))) void*)(gp), \
    (__attribute__((address_space(3))) void*)(lp), 16, 0, 0)

__device__ inline short f2bf(float f) {
    union { float f; uint32_t u; } v;
    v.f = f;
    uint32_t r = (v.u + 0x7FFFu + ((v.u >> 16) & 1u)) >> 16;
    return (short)(uint16_t)r;
}

__device__ inline bf16x8 cvt8(const float4& a, const float4& b) {
    bf16x8 o;
    o[0] = f2bf(a.x); o[1] = f2bf(a.y); o[2] = f2bf(a.z); o[3] = f2bf(a.w);
    o[4] = f2bf(b.x); o[5] = f2bf(b.y); o[6] = f2bf(b.z); o[7] = f2bf(b.w);
    return o;
}

__device__ inline uint32_t cvtpk(float lo, float hi) {
    uint32_t r;
    asm("v_cvt_pk_bf16_f32 %0, %1, %2" : "=v"(r) : "v"(lo), "v"(hi));
    return r;
}

__device__ inline bf16x8 mk8(uint32_t a, uint32_t b, uint32_t c, uint32_t d) {
    union { uint32_t u[4]; bf16x8 v; } t;
    t.u[0] = a; t.u[1] = b; t.u[2] = c; t.u[3] = d;
    return t.v;
}

// Verified shfl-based exchange (lane ^ 32).
__device__ inline void xchg_pf(const uint32_t c[8], bool hib, bf16x8& fA, bf16x8& fB) {
    uint32_t p0 = (uint32_t)__shfl_xor((int)c[0], 32);
    uint32_t p1 = (uint32_t)__shfl_xor((int)c[1], 32);
    uint32_t p2 = (uint32_t)__shfl_xor((int)c[2], 32);
    uint32_t p3 = (uint32_t)__shfl_xor((int)c[3], 32);
    fA = mk8(hib ? p2 : c[0], hib ? p3 : c[1], hib ? c[2] : p0, hib ? c[3] : p1);
    uint32_t p4 = (uint32_t)__shfl_xor((int)c[4], 32);
    uint32_t p5 = (uint32_t)__shfl_xor((int)c[5], 32);
    uint32_t p6 = (uint32_t)__shfl_xor((int)c[6], 32);
    uint32_t p7 = (uint32_t)__shfl_xor((int)c[7], 32);
    fB = mk8(hib ? p6 : c[4], hib ? p7 : c[5], hib ? c[6] : p4, hib ? c[7] : p5);
}

// Runtime-probe permlane32_swap semantics (round-11 verified working).
__device__ inline int probe_permlane_mode() {
#if defined(__has_builtin) && __has_builtin(__builtin_amdgcn_permlane32_swap)
    int lane = (int)(threadIdx.x & 63);
    int a = lane, b = lane + 1000;
    auto r = __builtin_amdgcn_permlane32_swap(a, b, false, false);
    int l0  = __builtin_amdgcn_readfirstlane(r[0]);
    int l32 = __builtin_amdgcn_readlane(r[0], 32);
    if (l0 == 0 && l32 == 1000) return 1;
    if (l0 == 1032 && l32 == 32) return 2;
    return 0;
#else
    return 0;
#endif
}

// ---------------- fused prep: 4x W-transpose + q/k/v f32->bf16 ----------------
__global__ __launch_bounds__(256) void prep(
    const float* __restrict__ Wq, const float* __restrict__ Wk,
    const float* __restrict__ Wv, const float* __restrict__ Wo,
    short* __restrict__ WqT, short* __restrict__ WkT,
    short* __restrict__ WvT, short* __restrict__ WoT,
    const float* __restrict__ q, const float* __restrict__ k, const float* __restrict__ v,
    short* __restrict__ Xq, short* __restrict__ Xk, short* __restrict__ Xv)
{
    __shared__ short Tt[64][65];
    const int K = 2048;
    int bid = blockIdx.x;
    int t = threadIdx.x;
    if (bid < 2560) {
        const float* W; short* T; int N; int l;
        if (bid < 1024)      { W = Wq; T = WqT; N = 2048; l = bid; }
        else if (bid < 1280) { W = Wk; T = WkT; N = 512;  l = bid - 1024; }
        else if (bid < 1536) { W = Wv; T = WvT; N = 512;  l = bid - 1280; }
        else                 { W = Wo; T = WoT; N = 2048; l = bid - 1536; }
        int nt = N >> 6;
        int n0 = (l % nt) * 64, k0 = (l / nt) * 64;
        int kl = t >> 2, nb = (t & 3) * 16;
        const float* wp = W + (size_t)(k0 + kl) * N + n0 + nb;
        #pragma unroll
        for (int j = 0; j < 16; ++j) Tt[nb + j][kl] = f2bf(wp[j]);
        __syncthreads();
        int nl = t >> 2, kb = (t & 3) * 16;
        short* op = T + (size_t)(n0 + nl) * K + k0 + kb;
        #pragma unroll
        for (int j = 0; j < 16; ++j) op[j] = Tt[nl][kb + j];
    } else {
        size_t tid = (size_t)(bid - 2560) * 256 + t;
        #pragma unroll
        for (int it = 0; it < 2; ++it) {
            size_t i = tid + (size_t)it * 524288;
            const float4* p;
            p = (const float4*)(q + i * 8);
            *(bf16x8*)(Xq + i * 8) = cvt8(p[0], p[1]);
            p = (const float4*)(k + i * 8);
            *(bf16x8*)(Xk + i * 8) = cvt8(p[0], p[1]);
            p = (const float4*)(v + i * 8);
            *(bf16x8*)(Xv + i * 8) = cvt8(p[0], p[1]);
        }
    }
}

// ---------------- fallback helpers ----------------
__global__ __launch_bounds__(256) void prepW(
    const float* __restrict__ Wq, const float* __restrict__ Wk,
    const float* __restrict__ Wv, const float* __restrict__ Wo,
    short* __restrict__ WqT, short* __restrict__ WkT,
    short* __restrict__ WvT, short* __restrict__ WoT)
{
    __shared__ short Tt[64][65];
    const int K = 2048;
    int bid = blockIdx.x;
    int t = threadIdx.x;
    const float* W; short* T; int N; int l;
    if (bid < 1024)      { W = Wq; T = WqT; N = 2048; l = bid; }
    else if (bid < 1280) { W = Wk; T = WkT; N = 512;  l = bid - 1024; }
    else if (bid < 1536) { W = Wv; T = WvT; N = 512;  l = bid - 1280; }
    else                 { W = Wo; T = WoT; N = 2048; l = bid - 1536; }
    int nt = N >> 6;
    int n0 = (l % nt) * 64, k0 = (l / nt) * 64;
    int kl = t >> 2, nb = (t & 3) * 16;
    const float* wp = W + (size_t)(k0 + kl) * N + n0 + nb;
    #pragma unroll
    for (int j = 0; j < 16; ++j) Tt[nb + j][kl] = f2bf(wp[j]);
    __syncthreads();
    int nl = t >> 2, kb = (t & 3) * 16;
    short* op = T + (size_t)(n0 + nl) * K + k0 + kb;
    #pragma unroll
    for (int j = 0; j < 16; ++j) op[j] = Tt[nl][kb + j];
}

__global__ __launch_bounds__(256) void cvtk(const float* __restrict__ in,
                                            short* __restrict__ out, int n8)
{
    int i = blockIdx.x * blockDim.x + threadIdx.x;
    int stride = gridDim.x * blockDim.x;
    for (; i < n8; i += stride) {
        const float4* p = (const float4*)(in + (size_t)i * 8);
        *(bf16x8*)(out + (size_t)i * 8) = cvt8(p[0], p[1]);
    }
}

__global__ __launch_bounds__(256) void transV(const short* __restrict__ Vb,
                                              short* __restrict__ Vt)
{
    __shared__ short T[64][65];
    int s0 = blockIdx.x * 64, d0 = blockIdx.y * 64, bg = blockIdx.z;
    int b = bg >> 2, g = bg & 3;
    int t = threadIdx.x;
    int sl = t >> 2, db = (t & 3) * 16;
    const short* vp = Vb + (size_t)(b * 2048 + s0 + sl) * 512 + g * 128 + d0 + db;
    #pragma unroll
    for (int j = 0; j < 16; ++j) T[db + j][sl] = vp[j];
    __syncthreads();
    int dl = t >> 2, sb = (t & 3) * 16;
    short* op = Vt + (size_t)(bg * 128 + d0 + dl) * 2048 + s0 + sb;
    #pragma unroll
    for (int j = 0; j < 16; ++j) op[j] = T[dl][sb + j];
}

// ---------------- bf16 GEMM core ----------------
template <typename TC>
__device__ __forceinline__ void gemm_core(
    const short* __restrict__ A, const short* __restrict__ BT,
    const float* __restrict__ bias, TC* __restrict__ C,
    int N, int K, int m0, int n0, short* As, short* Bs, int epi)
{
    const int t = threadIdx.x, w = t >> 6, lane = t & 63;
    const int lr = lane & 15, lg = lane >> 4;
    const int wm = (w >> 1) * 64, wn = (w & 1) * 64;
    f32x4 acc[4][4] = {};

    const int lrow = lane >> 3;
    const int lcg = (lane & 7) ^ (lrow & 7);
    const int sw = lr & 7;

    const short* abase[2]; const short* bbase[2];
    #pragma unroll
    for (int kc = 0; kc < 2; ++kc) {
        abase[kc] = &As[(wm + lr) * 64 + (((kc * 4 + lg) ^ sw) * 8)];
        bbase[kc] = &Bs[(wn + lr) * 64 + (((kc * 4 + lg) ^ sw) * 8)];
    }
    const short* asrc = A  + (size_t)(m0 + w * 32 + lrow) * K + lcg * 8;
    const short* bsrc = BT + (size_t)(n0 + w * 32 + lrow) * K + lcg * 8;
    short* adst = &As[(w * 32) * 64];
    short* bdst = &Bs[(w * 32) * 64];

    for (int kk = 0; kk < K; kk += 64) {
        __syncthreads();
        #pragma unroll
        for (int i = 0; i < 4; ++i) {
            GLL16(asrc + (size_t)i * 8 * K, adst + i * 512);
            GLL16(bsrc + (size_t)i * 8 * K, bdst + i * 512);
        }
        asrc += 64; bsrc += 64;
        __syncthreads();
        #pragma unroll
        for (int kc = 0; kc < 2; ++kc) {
            bf16x8 af[4], bfr[4];
            #pragma unroll
            for (int i = 0; i < 4; ++i) af[i] = *(const bf16x8*)(abase[kc] + i * 1024);
            #pragma unroll
            for (int j = 0; j < 4; ++j) bfr[j] = *(const bf16x8*)(bbase[kc] + j * 1024);
            #pragma unroll
            for (int i = 0; i < 4; ++i)
                #pragma unroll
                for (int j = 0; j < 4; ++j)
                    acc[i][j] = __builtin_amdgcn_mfma_f32_16x16x32_bf16(af[i], bfr[j], acc[i][j], 0, 0, 0);
        }
    }

    if constexpr (std::is_same<TC, short>::value) {
        if (epi == 1) {
            #pragma unroll
            for (int i = 0; i < 4; ++i) {
                #pragma unroll
                for (int j = 0; j < 4; ++j) {
                    int row = m0 + wm + i * 16 + lg * 4;
                    int col = n0 + wn + j * 16 + lr;
                    short4v s4;
                    #pragma unroll
                    for (int r = 0; r < 4; ++r) s4[r] = f2bf(acc[i][j][r] + bias[col]);
                    int bb = row >> 11, ss = row & 2047;
                    *(short4v*)((short*)C + ((size_t)(bb * 4 + (col >> 7)) * 128 + (col & 127)) * 2048 + ss) = s4;
                }
            }
            return;
        }
    }
    #pragma unroll
    for (int i = 0; i < 4; ++i) {
        #pragma unroll
        for (int j = 0; j < 4; ++j) {
            #pragma unroll
            for (int r = 0; r < 4; ++r) {
                int row = m0 + wm + i * 16 + lg * 4 + r;
                int col = n0 + wn + j * 16 + lr;
                float v = acc[i][j][r] + bias[col];
                if constexpr (std::is_same<TC, short>::value)
                    C[(size_t)row * N + col] = f2bf(v);
                else
                    C[(size_t)row * N + col] = v;
            }
        }
    }
}

template <typename TC>
__global__ __launch_bounds__(256) void gemm_std(
    const short* __restrict__ A, const short* __restrict__ BT,
    const float* __restrict__ bias, TC* __restrict__ C, int N, int K)
{
    __shared__ short As[128 * 64];
    __shared__ short Bs[128 * 64];
    int bid = blockIdx.x;
    int chunk = gridDim.x >> 3;
    int wg = (bid & 7) * chunk + (bid >> 3);
    int m0 = (wg & 31) * 128, n0 = (wg >> 5) * 128;
    gemm_core<TC>(A, BT, bias, C, N, K, m0, n0, As, Bs, 0);
}

__global__ __launch_bounds__(256) void gemm_qkv(
    const short* __restrict__ Xq, const short* __restrict__ Xk, const short* __restrict__ Xv,
    const short* __restrict__ WqT, const short* __restrict__ WkT, const short* __restrict__ WvT,
    const float* __restrict__ bq, const float* __restrict__ bk, const float* __restrict__ bv,
    short* __restrict__ Qb, short* __restrict__ Kb, short* __restrict__ Vt)
{
    __shared__ short As[128 * 64];
    __shared__ short Bs[128 * 64];
    int bid = blockIdx.x;
    int wg = (bid & 7) * 96 + (bid >> 3);
    const short* A; const short* BT; const float* bi; short* C; int N; int l; int epi;
    if (wg < 512)      { l = wg;       A = Xq; BT = WqT; bi = bq; C = Qb; N = 2048; epi = 0; }
    else if (wg < 640) { l = wg - 512; A = Xk; BT = WkT; bi = bk; C = Kb; N = 512;  epi = 0; }
    else               { l = wg - 640; A = Xv; BT = WvT; bi = bv; C = Vt; N = 512;  epi = 1; }
    int m0 = (l & 31) * 128, n0 = (l >> 5) * 128;
    gemm_core<short>(A, BT, bi, C, N, 2048, m0, n0, As, Bs, epi);
}

// ---------------- flash attention v11 (round-11 verified, 111.5 us) ----------------
__global__ __launch_bounds__(256, 2) void attn_kernel(
    const short* __restrict__ Qb, const short* __restrict__ Kb,
    const short* __restrict__ Vt, short* __restrict__ Ob)
{
    const int S = 2048;
    __shared__ short Ks[64 * 128];   // 16 KB, slot = c ^ (kv&15)
    __shared__ short Vs[128 * 64];   // 16 KB, slot = c ^ (d&7)

    int bid = blockIdx.x;
    int wg = (bid & 7) * 64 + (bid >> 3);
    const int qt = wg & 15, bh = wg >> 4;
    const int b = bh >> 4, h = bh & 15, g = h >> 2, bg = b * 4 + g;

    const int t = threadIdx.x, w = t >> 6, lane = t & 63;
    const int l5 = lane & 31, hi = lane >> 5;
    const bool hib = hi != 0;
    const int qg = b * S + qt * 128 + w * 32 + l5;
    const float C = 1.44269504089f;

    const int mode = probe_permlane_mode();

    const short* qrow = Qb + (size_t)qg * 2048 + h * 128 + hi * 8;
    bf16x8 qf[8];
    #pragma unroll
    for (int dm = 0; dm < 8; ++dm)
        qf[dm] = *(const bf16x8*)(qrow + dm * 16);

    f32x16 o[4] = {};
    float m = -1e30f, l = 0.0f;

    const int sr4 = lane >> 4, sc4 = lane & 15;
    const int sr8 = lane >> 3, sc8 = lane & 7;
    const short* ksrc[4]; const short* vsrc[4];
    #pragma unroll
    for (int i = 0; i < 4; ++i) {
        int kr = w * 16 + i * 4 + sr4;
        ksrc[i] = Kb + (size_t)(b * S + kr) * 512 + g * 128 + ((sc4 ^ (kr & 15)) * 8);
        int d = w * 32 + i * 8 + sr8;
        vsrc[i] = Vt + (size_t)(bg * 128 + d) * 2048 + ((sc8 ^ (d & 7)) * 8);
    }

    int kx[8];
    #pragma unroll
    for (int dm = 0; dm < 8; ++dm)
        kx[dm] = (((dm * 2 + hi) ^ (l5 & 15)) * 8);
    int va[4];
    #pragma unroll
    for (int j = 0; j < 4; ++j)
        va[j] = (((2 * j + hi) ^ (l5 & 7)) * 8);

    short* kd = Ks + (w * 16) * 128 + lane * 8;
    short* vd = Vs + (w * 32) * 64 + lane * 8;

    bf16x8 kreg[4], vreg[4];
    #pragma unroll
    for (int i = 0; i < 4; ++i) {
        kreg[i] = *(const bf16x8*)(ksrc[i]);
        vreg[i] = *(const bf16x8*)(vsrc[i]);
    }

    const int NT = S / 64;
    for (int ti = 0; ti < NT; ++ti) {
        __syncthreads();
        #pragma unroll
        for (int i = 0; i < 4; ++i) {
            *(bf16x8*)(kd + i * 512) = kreg[i];
            *(bf16x8*)(vd + i * 512) = vreg[i];
        }
        __syncthreads();
        if (ti + 1 < NT) {
            size_t ko = (size_t)(ti + 1) * 64 * 512;
            int vo = (ti + 1) * 64;
            #pragma unroll
            for (int i = 0; i < 4; ++i) {
                kreg[i] = *(const bf16x8*)(ksrc[i] + ko);
                vreg[i] = *(const bf16x8*)(vsrc[i] + vo);
            }
        }

        // ---- QK^T (swapped) ----
        const short* KB = Ks + l5 * 128;
        f32x16 p0 = {}, p1 = {};
        __builtin_amdgcn_s_setprio(1);
        #pragma unroll
        for (int dm = 0; dm < 8; ++dm) {
            bf16x8 k0 = *(const bf16x8*)(KB + kx[dm]);
            bf16x8 k1 = *(const bf16x8*)(KB + 4096 + kx[dm]);
            p0 = __builtin_amdgcn_mfma_f32_32x32x16_bf16(k0, qf[dm], p0, 0, 0, 0);
            p1 = __builtin_amdgcn_mfma_f32_32x32x16_bf16(k1, qf[dm], p1, 0, 0, 0);
        }
        __builtin_amdgcn_s_setprio(0);

        // ---- online softmax (round-11 exact path) ----
        float mx = -1e30f;
        #pragma unroll
        for (int e = 0; e < 16; ++e) mx = fmaxf(mx, fmaxf(p0[e], p1[e]));
        mx = fmaxf(mx, __shfl_xor(mx, 32));
        if (__any(mx > m)) {
            float mn = fmaxf(m, mx);
            float sf = exp2f((m - mn) * C);
            m = mn; l *= sf;
            #pragma unroll
            for (int dblk = 0; dblk < 4; ++dblk)
                #pragma unroll
                for (int e = 0; e < 16; ++e) o[dblk][e] *= sf;
        }
        float nmc = -m * C;
        #pragma unroll
        for (int e = 0; e < 16; ++e) {
            p0[e] = exp2f(fmaf(p0[e], C, nmc));
            p1[e] = exp2f(fmaf(p1[e], C, nmc));
        }
        float rs = 0.0f;
        #pragma unroll
        for (int e = 0; e < 16; ++e) rs += p0[e] + p1[e];
        rs += __shfl_xor(rs, 32);
        l += rs;

        // ---- P -> bf16 B-fragments ----
        uint32_t c0[8], c1[8];
        #pragma unroll
        for (int i = 0; i < 8; ++i) {
            c0[i] = cvtpk(p0[2 * i], p0[2 * i + 1]);
            c1[i] = cvtpk(p1[2 * i], p1[2 * i + 1]);
        }
        bf16x8 pf[4];
#if defined(__has_builtin) && __has_builtin(__builtin_amdgcn_permlane32_swap)
        if (mode == 1) {
            auto a0 = __builtin_amdgcn_permlane32_swap((int)c0[0], (int)c0[2], false, false);
            auto a1 = __builtin_amdgcn_permlane32_swap((int)c0[1], (int)c0[3], false, false);
            auto a2 = __builtin_amdgcn_permlane32_swap((int)c0[4], (int)c0[6], false, false);
            auto a3 = __builtin_amdgcn_permlane32_swap((int)c0[5], (int)c0[7], false, false);
            pf[0] = mk8((uint32_t)a0[0], (uint32_t)a1[0], (uint32_t)a0[1], (uint32_t)a1[1]);
            pf[1] = mk8((uint32_t)a2[0], (uint32_t)a3[0], (uint32_t)a2[1], (uint32_t)a3[1]);
            auto b0 = __builtin_amdgcn_permlane32_swap((int)c1[0], (int)c1[2], false, false);
            auto b1 = __builtin_amdgcn_permlane32_swap((int)c1[1], (int)c1[3], false, false);
            auto b2 = __builtin_amdgcn_permlane32_swap((int)c1[4], (int)c1[6], false, false);
            auto b3 = __builtin_amdgcn_permlane32_swap((int)c1[5], (int)c1[7], false, false);
            pf[2] = mk8((uint32_t)b0[0], (uint32_t)b1[0], (uint32_t)b0[1], (uint32_t)b1[1]);
            pf[3] = mk8((uint32_t)b2[0], (uint32_t)b3[0], (uint32_t)b2[1], (uint32_t)b3[1]);
        } else if (mode == 2) {
            auto a0 = __builtin_amdgcn_permlane32_swap((int)c0[2], (int)c0[0], false, false);
            auto a1 = __builtin_amdgcn_permlane32_swap((int)c0[3], (int)c0[1], false, false);
            auto a2 = __builtin_amdgcn_permlane32_swap((int)c0[6], (int)c0[4], false, false);
            auto a3 = __builtin_amdgcn_permlane32_swap((int)c0[7], (int)c0[5], false, false);
            pf[0] = mk8((uint32_t)a0[1], (uint32_t)a1[1], (uint32_t)a0[0], (uint32_t)a1[0]);
            pf[1] = mk8((uint32_t)a2[1], (uint32_t)a3[1], (uint32_t)a2[0], (uint32_t)a3[0]);
            auto b0 = __builtin_amdgcn_permlane32_swap((int)c1[2], (int)c1[0], false, false);
            auto b1 = __builtin_amdgcn_permlane32_swap((int)c1[3], (int)c1[1], false, false);
            auto b2 = __builtin_amdgcn_permlane32_swap((int)c1[6], (int)c1[4], false, false);
            auto b3 = __builtin_amdgcn_permlane32_swap((int)c1[7], (int)c1[5], false, false);
            pf[2] = mk8((uint32_t)b0[1], (uint32_t)b1[1], (uint32_t)b0[0], (uint32_t)b1[0]);
            pf[3] = mk8((uint32_t)b2[1], (uint32_t)b3[1], (uint32_t)b2[0], (uint32_t)b3[0]);
        } else
#endif
        {
            xchg_pf(c0, hib, pf[0], pf[1]);
            xchg_pf(c1, hib, pf[2], pf[3]);
        }

        // ---- PV ----
        const short* VB = Vs + l5 * 64;
        __builtin_amdgcn_s_setprio(1);
        #pragma unroll
        for (int dblk = 0; dblk < 4; ++dblk) {
            const short* vb = VB + dblk * 2048;
            #pragma unroll
            for (int j = 0; j < 4; ++j) {
                bf16x8 vf = *(const bf16x8*)(vb + va[j]);
                o[dblk] = __builtin_amdgcn_mfma_f32_32x32x16_bf16(vf, pf[j], o[dblk], 0, 0, 0);
            }
        }
        __builtin_amdgcn_s_setprio(0);
    }

    float inv = 1.0f / l;
    short* op = Ob + (size_t)qg * 2048 + h * 128 + hi * 4;
    #pragma unroll
    for (int dblk = 0; dblk < 4; ++dblk) {
        #pragma unroll
        for (int mm = 0; mm < 4; ++mm) {
            short4v s4;
            #pragma unroll
            for (int e = 0; e < 4; ++e) s4[e] = f2bf(o[dblk][mm * 4 + e] * inv);
            *(short4v*)(op + dblk * 32 + mm * 8) = s4;
        }
    }
}

extern "C" void kernel_launch(void* const* d_in, const int* in_sizes, int n_in,
                              void* d_out, int out_size, void* d_ws, size_t ws_size,
                              hipStream_t stream)
{
    const float* query = (const float*)d_in[0];
    const float* key   = (const float*)d_in[1];
    const float* value = (const float*)d_in[2];
    const float* Wq    = (const float*)d_in[3];
    const float* bq    = (const float*)d_in[4];
    const float* Wk    = (const float*)d_in[5];
    const float* bk    = (const float*)d_in[6];
    const float* Wv    = (const float*)d_in[7];
    const float* bv    = (const float*)d_in[8];
    const float* Wo    = (const float*)d_in[9];
    const float* bo    = (const float*)d_in[10];
    float* out = (float*)d_out;

    const int BS = 4096;
    char* ws = (char*)d_ws;
    dim3 blk(256);
    const size_t MB = 1048576;

    if (ws_size >= 96 * MB) {
        short* Xq  = (short*)(ws + 0);
        short* Xk  = (short*)(ws + 16 * MB);
        short* Xv  = (short*)(ws + 32 * MB);
        short* Qb  = (short*)(ws + 48 * MB);
        short* Kb  = (short*)(ws + 64 * MB);
        short* Vtg = (short*)(ws + 72 * MB);
        short* WqT = (short*)(ws + 76 * MB);
        short* WkT = (short*)(ws + 84 * MB);
        short* WvT = (short*)(ws + 86 * MB);
        short* WoT = (short*)(ws + 88 * MB);
        short* Ob  = Xq;  // Xq dead after gemm_qkv

        prep<<<4608, blk, 0, stream>>>(Wq, Wk, Wv, Wo, WqT, WkT, WvT, WoT,
                                       query, key, value, Xq, Xk, Xv);
        gemm_qkv<<<768, blk, 0, stream>>>(Xq, Xk, Xv, WqT, WkT, WvT, bq, bk, bv, Qb, Kb, Vtg);
        attn_kernel<<<512, blk, 0, stream>>>(Qb, Kb, Vtg, Ob);
        gemm_std<float><<<512, blk, 0, stream>>>(Ob, WoT, bo, out, 2048, 2048);
    } else {
        short* Qb  = (short*)(ws + 0);
        short* Kb  = (short*)(ws + 16777216);
        short* Vb  = (short*)(ws + 20971520);
        short* Vtg = (short*)(ws + 25165824);
        short* WqT = (short*)(ws + 29360128);
        short* WkT = (short*)(ws + 37748736);
        short* WvT = (short*)(ws + 39845888);
        short* WoT = (short*)(ws + 41943040);
        short* Xbf = (short*)(ws + 50331648);

        prepW<<<2560, blk, 0, stream>>>(Wq, Wk, Wv, Wo, WqT, WkT, WvT, WoT);
        cvtk<<<2048, blk, 0, stream>>>(query, Xbf, BS * 2048 / 8);
        gemm_std<short><<<512, blk, 0, stream>>>(Xbf, WqT, bq, Qb, 2048, 2048);
        cvtk<<<2048, blk, 0, stream>>>(key, Xbf, BS * 2048 / 8);
        gemm_std<short><<<128, blk, 0, stream>>>(Xbf, WkT, bk, Kb, 512, 2048);
        cvtk<<<2048, blk, 0, stream>>>(value, Xbf, BS * 2048 / 8);
        gemm_std<short><<<128, blk, 0, stream>>>(Xbf, WvT, bv, Vb, 512, 2048);
        transV<<<dim3(32, 2, 8), blk, 0, stream>>>(Vb, Vtg);
        attn_kernel<<<512, blk, 0, stream>>>(Qb, Kb, Vtg, Xbf);
        gemm_std<float><<<512, blk, 0, stream>>>(Xbf, WoT, bo, out, 2048, 2048);
    }
}